// Round 11
// baseline (115.860 us; speedup 1.0000x reference)
//
#include <hip/hip_runtime.h>

// NeRF fused kernel for MI355X (gfx950) — round 11.
// r10 post-mortem: LDS-staging W2 was NEUTRAL (43.3 vs 42.0) — K-loop load
// latency was already covered. Idle ~30% persists across r7/r9/r10 probes:
// it is serial per-wave latency (po/pd chain, render's ~12 dependent
// cross-lane ops, heads) uncoverable at 2 waves/SIMD (reg-capped by
// acc[8][4]=128 AGPR). Fix: r7's half-ray waves (acc[8][2]=64 AGPR, proven
// no-spill at (256,3)) + r10's LDS-staged W2 (kills r7's fatal 3x W2 VMEM
// traffic). 3 blocks/CU co-resident -> 3 waves/SIMD, staggered heads/tails.
//   block = 2 rays, wave w: ray w>>1, samples (w&1)*32..+32.
//   W2 read once per block (32 KB from L2) -> LDS; frags via ds_read_b128.
//   Verified h2-permutation register hand-off (phase-2 D == phase-3 B).
//   w3/bk loads deferred past phase 2 (peak live ~140 regs < 170 cap).

typedef _Float16 f16;
typedef __attribute__((ext_vector_type(2))) _Float16 h2v;
typedef __attribute__((ext_vector_type(8))) _Float16 half8;
typedef __attribute__((ext_vector_type(4))) float floatx4;

#define H 128
#define NS 64

static __device__ __forceinline__ h2v pkrtz(float a, float b) {
  return __builtin_bit_cast(h2v, __builtin_amdgcn_cvt_pkrtz(a, b));
}

// ---------------------------------------------------------------------------
// Setup (identical to rounds 5/6/10, HW-verified): W2 -> A-frags with
// permuted h2 columns n = 32*(l16>>2) + mt*4 + (l16&3); W3 -> A-frags with
// matching permuted rows k3 = 32*(lane>>4) + ks*8 + j (cols padded to 16);
// b2 natural order.
// ---------------------------------------------------------------------------
__global__ void nerf_setup(const float* __restrict__ W2, const float* __restrict__ W3,
                           const float* __restrict__ b2,
                           f16* __restrict__ wsW2, f16* __restrict__ wsW3,
                           f16* __restrict__ wsB2) {
  int t = blockIdx.x * blockDim.x + threadIdx.x;
  if (t < 8192) {                       // W2 frags
    int j2 = t & 3, lane = (t >> 2) & 63, mt = (t >> 8) & 7, ks = t >> 11;
    int l16 = lane & 15;
    int k = ks * 32 + ((lane >> 4) * 8) + 2 * j2;
    int n = 32 * (l16 >> 2) + mt * 4 + (l16 & 3);    // permuted column
    wsW2[2 * t]     = (f16)W2[k * H + n];
    wsW2[2 * t + 1] = (f16)W2[(k + 1) * H + n];
  } else if (t < 9216) {                // W3 frags (A-layout, permuted rows, padded)
    int u = t - 8192;
    int j2 = u & 3, lane = (u >> 2) & 63, ks = u >> 8;
    int c = lane & 15;
    int k3 = 32 * (lane >> 4) + ks * 8 + 2 * j2;     // permuted h2 feature
    wsW3[2 * u]     = (c < 4) ? (f16)W3[k3 * 4 + c]       : (f16)0.0f;
    wsW3[2 * u + 1] = (c < 4) ? (f16)W3[(k3 + 1) * 4 + c] : (f16)0.0f;
  } else if (t < 9344) {                // b2, natural order f16
    int i = t - 9216;
    wsB2[i] = (f16)b2[i];
  }
}

// ---------------------------------------------------------------------------
// Main: block = 2 rays = 4 waves; wave = half ray (32 points); 2 barriers.
// ---------------------------------------------------------------------------
__global__ __launch_bounds__(256, 3) void nerf_main(
    const float* __restrict__ origins, const float* __restrict__ dirs,
    const float* __restrict__ W1, const float* __restrict__ b1,
    const float* __restrict__ b3,
    const f16* __restrict__ wsW2, const f16* __restrict__ wsW3,
    const f16* __restrict__ wsB2,
    float* __restrict__ out)
{
  __shared__ __align__(16) f16   w2s[16384];      // staged W2 frags (32 KB)
  __shared__ __align__(16) f16   popd[2][2][H];   // per-ray po/pd strips (1 KB)
  __shared__ __align__(16) float f_lds[2][64][4]; // render transpose (2 KB)

  const int t = threadIdx.x;
  const int w = t >> 6, lane = t & 63, quad = lane >> 4, l16 = lane & 15;
  const int rayw  = w >> 1;            // ray within block (0/1)
  const int shalf = (w & 1) * 32;      // this wave's sample offset in the ray
  const float delta = 4.0f / NS;       // near=2, far=6 baked

  // ---- Stage W2 frag table into LDS (32 KB, coalesced 16B chunks) ----
  {
    const uint4* src = (const uint4*)wsW2;
    uint4* dst = (uint4*)w2s;
    #pragma unroll
    for (int c = 0; c < 8; ++c)
      dst[t + c * 256] = src[t + c * 256];
  }

  // ---- po/pd: waves 0,1 compute for rays 0,1 ----
  if (w < 2) {
    const int ray = blockIdx.x * 2 + w;
    const float o0 = origins[ray*3], o1 = origins[ray*3+1], o2 = origins[ray*3+2];
    const float d0 = dirs[ray*3],    d1 = dirs[ray*3+1],    d2 = dirs[ray*3+2];
    const int k0 = lane * 2;
    const float2 wr0 = *(const float2*)&W1[0*H + k0];
    const float2 wr1 = *(const float2*)&W1[1*H + k0];
    const float2 wr2 = *(const float2*)&W1[2*H + k0];
    const float2 bb  = *(const float2*)&b1[k0];
    float poa = fmaf(o2, wr2.x, fmaf(o1, wr1.x, fmaf(o0, wr0.x, bb.x)));
    float pob = fmaf(o2, wr2.y, fmaf(o1, wr1.y, fmaf(o0, wr0.y, bb.y)));
    float pda = fmaf(d2, wr2.x, fmaf(d1, wr1.x, d0 * wr0.x));
    float pdb = fmaf(d2, wr2.y, fmaf(d1, wr1.y, d0 * wr0.y));
    h2v po2; po2[0] = (f16)poa; po2[1] = (f16)pob;
    h2v pd2; pd2[0] = (f16)pda; pd2[1] = (f16)pdb;
    *(h2v*)&popd[w][0][k0] = po2;
    *(h2v*)&popd[w][1][k0] = pd2;
  }
  __syncthreads();   // staging + popd complete

  // m splats: sample s = shalf + tr*16 + l16; m exact in f16 (multiple of 1/32)
  half8 m8[2];
  #pragma unroll
  for (int tr = 0; tr < 2; ++tr)
    m8[tr] = (half8)(f16)(2.0f + (shalf + tr*16 + l16 + 0.5f) * delta);

  // ---- Phase 2: h2'^T = W2'^T @ h1^T; 4 ks x 2 tr x 8 mt MFMAs.
  // Frags from LDS: frag f at w2s[f*512 + lane*8] (16B/lane, m97-pattern). ----
  floatx4 acc[8][2];
  #pragma unroll
  for (int mt = 0; mt < 8; ++mt) {
    acc[mt][0] = (floatx4)(0.0f);
    acc[mt][1] = (floatx4)(0.0f);
  }

  const half8 z8 = (half8)(f16)0.0f;
  #pragma unroll
  for (int ks = 0; ks < 4; ++ks) {
    half8 aw[8];
    #pragma unroll
    for (int mt = 0; mt < 8; ++mt)
      aw[mt] = *(const half8*)&w2s[(ks*8 + mt)*512 + lane*8];
    const half8 po8 = *(const half8*)&popd[rayw][0][ks*32 + quad*8];
    const half8 pd8 = *(const half8*)&popd[rayw][1][ks*32 + quad*8];
    #pragma unroll
    for (int tr = 0; tr < 2; ++tr) {
      half8 hb = pd8 * m8[tr] + po8;                 // v_pk_fma_f16 x4
      hb = __builtin_elementwise_max(hb, z8);        // v_pk_max_f16 x4
      #pragma unroll
      for (int mt = 0; mt < 8; ++mt)
        acc[mt][tr] = __builtin_amdgcn_mfma_f32_16x16x32_f16(aw[mt], hb, acc[mt][tr], 0, 0, 0);
    }
  }

  // ---- Phase 3 (fused epilogue): f^T = W3'^T @ h2'^T. B-frags straight from
  // acc (permutation hand-off). w3/bk loaded HERE to cap phase-2 reg peak. ----
  h2v bk0[8], bk1[8];
  {
    const uint2* bp = (const uint2*)wsB2;
    #pragma unroll
    for (int mt = 0; mt < 8; ++mt) {
      uint2 u = bp[quad * 8 + mt];                   // b2[32q+4mt .. +3]
      bk0[mt] = __builtin_bit_cast(h2v, u.x);
      bk1[mt] = __builtin_bit_cast(h2v, u.y);
    }
  }
  const half8* w3f = (const half8*)wsW3;
  half8 w3[4];
  #pragma unroll
  for (int ks = 0; ks < 4; ++ks) w3[ks] = w3f[ks*64 + lane];

  const h2v z2 = (h2v)(f16)0.0f;
  floatx4 acc3[2];
  #pragma unroll
  for (int tr = 0; tr < 2; ++tr) {
    acc3[tr] = (floatx4)(0.0f);
    #pragma unroll
    for (int ks = 0; ks < 4; ++ks) {
      const int mt0 = 2*ks, mt1 = 2*ks + 1;
      h2v c0 = __builtin_elementwise_max((h2v)(pkrtz(acc[mt0][tr][0], acc[mt0][tr][1]) + bk0[mt0]), z2);
      h2v c1 = __builtin_elementwise_max((h2v)(pkrtz(acc[mt0][tr][2], acc[mt0][tr][3]) + bk1[mt0]), z2);
      h2v c2 = __builtin_elementwise_max((h2v)(pkrtz(acc[mt1][tr][0], acc[mt1][tr][1]) + bk0[mt1]), z2);
      h2v c3 = __builtin_elementwise_max((h2v)(pkrtz(acc[mt1][tr][2], acc[mt1][tr][3]) + bk1[mt1]), z2);
      half8 b = { c0[0], c0[1], c1[0], c1[1], c2[0], c2[1], c3[0], c3[1] };
      acc3[tr] = __builtin_amdgcn_mfma_f32_16x16x32_f16(w3[ks], b, acc3[tr], 0, 0, 0);
    }
  }

  // D3: lane holds f[m = quad*4+r][point tr*16+l16]; quad 0 rows = (R,G,B,sigma).
  if (quad == 0) {
    const float4 b3v = *(const float4*)b3;
    #pragma unroll
    for (int tr = 0; tr < 2; ++tr) {
      float4 fv;
      fv.x = acc3[tr][0] + b3v.x;
      fv.y = acc3[tr][1] + b3v.y;
      fv.z = acc3[tr][2] + b3v.z;
      fv.w = acc3[tr][3] + b3v.w;
      *(float4*)&f_lds[rayw][shalf + tr*16 + l16][0] = fv;   // ds_write_b128
    }
  }
  __syncthreads();   // ray spans 2 waves

  // ---- Phase 4: volume rendering, waves 0,1 render rays 0,1 ----
  if (w < 2) {
    const int rray = blockIdx.x * 2 + w;
    const float4 fv = *(const float4*)&f_lds[w][lane][0];
    const float sigma = fv.w;
    const float alpha = 1.0f - __expf(-sigma * delta);
    float S = sigma;
    #pragma unroll
    for (int off = 1; off < 64; off <<= 1) {
      float u = __shfl_up(S, off);
      if (lane >= off) S += u;
    }
    const float T  = __expf(-delta * (S - sigma));   // exclusive prefix
    const float wt = alpha * T;
    float cr = wt * fv.x, cg = wt * fv.y, cb = wt * fv.z;
    #pragma unroll
    for (int off = 32; off > 0; off >>= 1) {
      cr += __shfl_down(cr, off);
      cg += __shfl_down(cg, off);
      cb += __shfl_down(cb, off);
    }
    if (lane == 0) {
      out[rray*3+0] = cr; out[rray*3+1] = cg; out[rray*3+2] = cb;
    }
  }
}

extern "C" void kernel_launch(void* const* d_in, const int* in_sizes, int n_in,
                              void* d_out, int out_size, void* d_ws, size_t ws_size,
                              hipStream_t stream) {
  const float* origins = (const float*)d_in[0];
  const float* dirs    = (const float*)d_in[1];
  const float* W1      = (const float*)d_in[2];
  const float* b1      = (const float*)d_in[3];
  const float* W2      = (const float*)d_in[4];
  const float* b2      = (const float*)d_in[5];
  const float* W3      = (const float*)d_in[6];
  const float* b3      = (const float*)d_in[7];
  float* out = (float*)d_out;

  f16* wsW2 = (f16*)d_ws;          // 16384 f16 = 32 KB
  f16* wsW3 = wsW2 + 16384;        // 2048 f16  = 4 KB
  f16* wsB2 = wsW3 + 2048;         // 128 f16   = 256 B

  nerf_setup<<<37, 256, 0, stream>>>(W2, W3, b2, wsW2, wsW3, wsB2);
  nerf_main<<<16384 / 2, 256, 0, stream>>>(
      origins, dirs, W1, b1, b3, wsW2, wsW3, wsB2, out);
}